// Round 1
// baseline (109.674 us; speedup 1.0000x reference)
//
#include <hip/hip_runtime.h>
#include <math.h>

// CLUB_NCE: N=512, D=400, H=400.
// K1 : hidden GEMMs, FULL k=400 per block (no k-split -> no combine kernel).
//      Lane-dim operand staged in LDS in two 200-k chunks (52 KB, 3 blk/CU),
//      4 wave-uniform scalar rows per thread (s_load path).
//      mat0 -> hxT[h][n]; mat1 -> hyb[n][h] with +b1 fused into the store.
//      Grid 424 = 200 (mat0) + 224 (mat1).
// K2 : pair scores. 2 i-rows per thread: each B-column value (hxT[h][j]) is
//      loaded once and reused for both i -> hxT L2 read traffic halves
//      (419 MB -> 210 MB). Grid (8 jx, 64 iy) = 512 blocks, 2 waves/SIMD.
//      No LDS / no barriers. Fused softplus + per-row fp64 wave reduction.
// K3 : fp64 logsumexp assembly -> (lower, upper).

#define NSAMP 512
#define DIM 400
#define HID 400

// ---------------- K1 ----------------
// blocks 0..199   : mat0: bx=b&7 -> n0=bx*64 (lane), by=b>>3 (0..24) -> h0=by*16
// blocks 200..423 : mat1: bb=b-200: bx=bb&31 -> n0=bx*16, by=bb>>5 (0..6) -> h0=by*64 (lane)
__global__ __launch_bounds__(256) void club_gemm_kernel(
    const float* __restrict__ X, const float* __restrict__ Y,
    const float* __restrict__ W1, const float* __restrict__ b1,
    float* __restrict__ hxT, float* __restrict__ hyb)
{
    __shared__ __align__(16) float Ls[64 * 204];   // 52224 B -> 3 blocks/CU
    const int t    = threadIdx.x;
    const int lane = t & 63;
    const int wave = __builtin_amdgcn_readfirstlane(t >> 6);
    const int b    = blockIdx.x;

    const float* __restrict__ Lbase;   // lane-dim matrix (LDS-staged)
    const float* __restrict__ Sbase;   // scalar-dim matrix (s_load)
    int Lstride, Lcol0, Lrow0, Lrowmax, Sstride, srow_base;
    int mat;

    if (b < 200) {                    // mat0
        mat = 0;
        const int bx = b & 7, by = b >> 3;
        Lbase = X;  Lstride = DIM;     Lcol0 = 0;   Lrow0 = bx * 64; Lrowmax = NSAMP - 1;
        Sbase = W1; Sstride = 2 * DIM;
        srow_base = by * 16 + wave * 4;             // h rows, max 384+12+3=399
    } else {                          // mat1
        mat = 1;
        const int bb = b - 200;
        const int bx = bb & 31, by = bb >> 5;
        Lbase = W1; Lstride = 2 * DIM; Lcol0 = DIM; Lrow0 = by * 64; Lrowmax = HID - 1;
        Sbase = Y;  Sstride = DIM;
        srow_base = bx * 16 + wave * 4;             // n rows, max 496+15=511
    }

    float acc[4] = {0.f, 0.f, 0.f, 0.f};

#pragma unroll 1
    for (int half = 0; half < 2; half++) {
        const int kc0 = half * 200;
        if (half) __syncthreads();     // protect LDS before re-staging

        // stage lane-dim tile: 64 rows x 200 k -> Ls, coalesced float4
        for (int idx = t; idx < 3200; idx += 256) {
            int row = idx / 50, q = idx % 50;
            int r = Lrow0 + row; if (r > Lrowmax) r = Lrowmax;
            float4 v = *(const float4*)(Lbase + (size_t)r * Lstride + Lcol0 + kc0 + 4 * q);
            *(float4*)(Ls + row * 204 + 4 * q) = v;
        }
        __syncthreads();

#pragma unroll 2
        for (int k4 = 0; k4 < 50; k4++) {
            float4 xv = *(const float4*)(Ls + lane * 204 + 4 * k4);
#pragma unroll
            for (int c = 0; c < 4; c++) {
                const float* __restrict__ wp =
                    Sbase + (size_t)(srow_base + c) * Sstride + kc0 + 4 * k4;  // uniform
                float4 wv = *(const float4*)wp;
                acc[c] = fmaf(xv.x, wv.x, acc[c]);
                acc[c] = fmaf(xv.y, wv.y, acc[c]);
                acc[c] = fmaf(xv.z, wv.z, acc[c]);
                acc[c] = fmaf(xv.w, wv.w, acc[c]);
            }
        }
    }

    if (mat == 0) {                   // store hxT[h][n], lane=n coalesced
#pragma unroll
        for (int c = 0; c < 4; c++)
            hxT[(size_t)(srow_base + c) * NSAMP + Lrow0 + lane] = acc[c];
    } else {                          // store hyb[n][h] (+b1), lane=h coalesced
        const int h = Lrow0 + lane;
        if (h < HID) {
            const float bv = b1[h];
#pragma unroll
            for (int c = 0; c < 4; c++)
                hyb[(size_t)(srow_base + c) * HID + h] = acc[c] + bv;
        }
    }
}

// ---------------- K2: pair scores, 2 i per thread, no LDS, no barriers ----------------
// grid (8 jx, 64 iy) = 512 blocks, 256 thr. lane=j, wave -> i-pair (8 i per block).
__global__ __launch_bounds__(256) void club_pair_kernel(
    const float* __restrict__ hxT, const float* __restrict__ hyb,
    const float* __restrict__ W2, const float* __restrict__ b2,
    double* __restrict__ expsum, double* __restrict__ tsum,
    double* __restrict__ diagT)
{
    const int t    = threadIdx.x;
    const int lane = t & 63;
    const int wave = __builtin_amdgcn_readfirstlane(t >> 6);
    const int jx   = blockIdx.x;
    const int j    = jx * 64 + lane;
    const int i0   = blockIdx.y * 8 + wave * 2;   // uniform
    const int i1   = i0 + 1;

    const float* __restrict__ Bp  = hxT + j;      // column j, stride NSAMP
    const float* __restrict__ Ap0 = hyb + (size_t)i0 * HID;
    const float* __restrict__ Ap1 = hyb + (size_t)i1 * HID;

    float a0s = 0.f, a1s = 0.f;   // acc for i0 (two chains)
    float b0s = 0.f, b1s = 0.f;   // acc for i1
#pragma unroll 2
    for (int g = 0; g < 50; g++) {
        const int h = 8 * g;
        float bv[8];
#pragma unroll
        for (int u = 0; u < 8; u++)
            bv[u] = Bp[(size_t)(h + u) * NSAMP];        // b32 coalesced, L2-hit
        float4 p0 = *(const float4*)(Ap0 + h);          // uniform -> s_load
        float4 p1 = *(const float4*)(Ap0 + h + 4);
        float4 q0 = *(const float4*)(Ap1 + h);
        float4 q1 = *(const float4*)(Ap1 + h + 4);
        float4 w0 = *(const float4*)(W2 + h);
        float4 w1 = *(const float4*)(W2 + h + 4);
        // i0
        a0s = fmaf(fmaxf(p0.x + bv[0], 0.f), w0.x, a0s);
        a1s = fmaf(fmaxf(p0.y + bv[1], 0.f), w0.y, a1s);
        a0s = fmaf(fmaxf(p0.z + bv[2], 0.f), w0.z, a0s);
        a1s = fmaf(fmaxf(p0.w + bv[3], 0.f), w0.w, a1s);
        a0s = fmaf(fmaxf(p1.x + bv[4], 0.f), w1.x, a0s);
        a1s = fmaf(fmaxf(p1.y + bv[5], 0.f), w1.y, a1s);
        a0s = fmaf(fmaxf(p1.z + bv[6], 0.f), w1.z, a0s);
        a1s = fmaf(fmaxf(p1.w + bv[7], 0.f), w1.w, a1s);
        // i1 (reuses bv)
        b0s = fmaf(fmaxf(q0.x + bv[0], 0.f), w0.x, b0s);
        b1s = fmaf(fmaxf(q0.y + bv[1], 0.f), w0.y, b1s);
        b0s = fmaf(fmaxf(q0.z + bv[2], 0.f), w0.z, b0s);
        b1s = fmaf(fmaxf(q0.w + bv[3], 0.f), w0.w, b1s);
        b0s = fmaf(fmaxf(q1.x + bv[4], 0.f), w1.x, b0s);
        b1s = fmaf(fmaxf(q1.y + bv[5], 0.f), w1.y, b1s);
        b0s = fmaf(fmaxf(q1.z + bv[6], 0.f), w1.z, b0s);
        b1s = fmaf(fmaxf(q1.w + bv[7], 0.f), w1.w, b1s);
    }

    // epilogue: softplus + fp64 reduction over the 64 j-lanes (both i rows)
    const float bias = b2[0];
    float s0  = (a0s + a1s) + bias;
    float s1  = (b0s + b1s) + bias;
    float es0 = expf(s0), es1 = expf(s1);
    float T0  = log1pf(es0);             // softplus
    float T1  = log1pf(es1);
    if (j == i0) diagT[i0] = (double)T0;
    if (j == i1) diagT[i1] = (double)T1;
    double e0 = 1.0 + (double)es0, t0 = (double)T0;   // exp(softplus(s)) exactly
    double e1 = 1.0 + (double)es1, t1 = (double)T1;
    for (int off = 32; off > 0; off >>= 1) {
        e0 += __shfl_down(e0, off);
        t0 += __shfl_down(t0, off);
        e1 += __shfl_down(e1, off);
        t1 += __shfl_down(t1, off);
    }
    if (lane == 0) {
        expsum[i0 * 8 + jx] = e0;
        tsum  [i0 * 8 + jx] = t0;
        expsum[i1 * 8 + jx] = e1;
        tsum  [i1 * 8 + jx] = t1;
    }
}

// ---------------- K3: final assembly ----------------
__global__ __launch_bounds__(512) void club_final_kernel(
    const double* __restrict__ expsum, const double* __restrict__ tsum,
    const double* __restrict__ diagT, float* __restrict__ out)
{
    __shared__ double sh[3 * 512];
    const int t = threadIdx.x;   // = i
    double es = 0.0, ts = 0.0;
#pragma unroll
    for (int b = 0; b < 8; b++) { es += expsum[t * 8 + b]; ts += tsum[t * 8 + b]; }
    sh[t] = log(es); sh[512 + t] = ts; sh[1024 + t] = diagT[t];
    __syncthreads();
    for (int off = 256; off > 0; off >>= 1) {
        if (t < off) {
            sh[t]        += sh[t + off];
            sh[512 + t]  += sh[512 + t + off];
            sh[1024 + t] += sh[1024 + t + off];
        }
        __syncthreads();
    }
    if (t == 0) {
        double t0m  = sh[1024] / 512.0;
        double lsem = sh[0]    / 512.0;
        double t1m  = sh[512]  / (512.0 * 512.0);
        out[0] = (float)(t0m - (lsem - log(512.0)));
        out[1] = (float)(t0m - t1m);
    }
}

extern "C" void kernel_launch(void* const* d_in, const int* in_sizes, int n_in,
                              void* d_out, int out_size, void* d_ws, size_t ws_size,
                              hipStream_t stream) {
    const float* X  = (const float*)d_in[0];
    const float* Y  = (const float*)d_in[1];
    const float* W1 = (const float*)d_in[2];
    const float* b1 = (const float*)d_in[3];
    const float* W2 = (const float*)d_in[4];
    const float* b2 = (const float*)d_in[5];
    float* out = (float*)d_out;

    char* ws = (char*)d_ws;
    float*  hxT    = (float*) (ws);                 // 400*512*4 = 819200
    float*  hyb    = (float*) (ws +  819200);       // 512*400*4 = 819200
    double* expsum = (double*)(ws + 1638400);       // 512*8*8 = 32768
    double* tsum   = (double*)(ws + 1671168);       // 32768
    double* diagT  = (double*)(ws + 1703936);       // 4096  -> ~1.71 MB total

    club_gemm_kernel <<<dim3(424),    256, 0, stream>>>(X, Y, W1, b1, hxT, hyb);
    club_pair_kernel <<<dim3(8, 64),  256, 0, stream>>>(hxT, hyb, W2, b2,
                                                        expsum, tsum, diagT);
    club_final_kernel<<<1, 512, 0, stream>>>(expsum, tsum, diagT, out);
}